// Round 5
// baseline (5033.428 us; speedup 1.0000x reference)
//
#include <hip/hip_runtime.h>
#include <math.h>

// Problem constants
#define T_STEPS 1024
#define BATCH   32
#define HID     512
#define G4      2048          // 4*HID
#define NWG     128           // total workgroups (64 per layer)
#define WGL     64            // WGs per layer
#define JPW     8             // h-columns owned per WG
#define FPAD    32            // flag stride in u32 (one 128B line per flag)
#define NSLOT   16            // ring depth (slots, indexed by t&15)

// ring layout: [slot][wg=col/8][row][8 cols] bf16 -> fragment (row, 8 cols) = 16B
#define RBYTES  (NSLOT * WGL * BATCH * 8 * 2)   // 512KB per ring

// workspace layout (bytes)
#define WS_FLAGS 0                       // 128 x 128B = 16KB
#define WS_H1    16384                   // h1 ring (L0 output)
#define WS_H2    (WS_H1 + RBYTES)        // h2 ring (L1 internal)
#define WS_XBF   (WS_H2 + RBYTES)        // x in bf16: 32MB (optional)

#define POIS16  0x7FC0                   // bf16 NaN: unreachable for |h|<=1
#define POIS32  0x7FC07FC0u

#define OUT_ELEMS (BATCH * T_STEPS * HID)
#define H_OFF OUT_ELEMS
#define C_OFF (OUT_ELEMS + 2 * BATCH * HID)

typedef __attribute__((ext_vector_type(8)))  short short8;
typedef __attribute__((ext_vector_type(16))) float f32x16;
typedef __attribute__((ext_vector_type(4)))  unsigned int u32x4;

__device__ __forceinline__ unsigned short f2bf(float f) {
    union { float f; unsigned u; } v; v.f = f;
    unsigned r = v.u + 0x7fffu + ((v.u >> 16) & 1u);   // RNE
    return (unsigned short)(r >> 16);
}
__device__ __forceinline__ float sigm(float x)  { return 1.0f / (1.0f + __expf(-x)); }
__device__ __forceinline__ float ftanh(float x) { return 1.0f - 2.0f / (__expf(2.0f * x) + 1.0f); }

// sc0+sc1: bypass L1/L2, read/write LLC directly (proven R2 protocol).
__device__ __forceinline__ short8 ld_llc(const void* p) {
    short8 r;
    asm volatile("global_load_dwordx4 %0, %1, off sc0 sc1" : "=v"(r) : "v"(p));
    return r;
}
__device__ __forceinline__ void st16_llc(void* p, u32x4 v) {
    asm volatile("global_store_dwordx4 %0, %1, off sc0 sc1" :: "v"(p), "v"(v) : "memory");
}

__device__ __forceinline__ void poll_ge(const unsigned* p, unsigned epoch) {
    while (__hip_atomic_load(p, __ATOMIC_RELAXED, __HIP_MEMORY_SCOPE_AGENT) < epoch)
        __builtin_amdgcn_s_sleep(1);
}

// Gather this thread's 8-group (row m, cols jbase..jbase+7) into lane jl==0
// and store as ONE 16B fragment (single store -> per-4B atomic at LLC).
__device__ __forceinline__ void publish_row(unsigned short* dst16, float hv, int tid) {
    unsigned hb = (unsigned)f2bf(hv);
    unsigned v0 = hb | (((unsigned)__shfl_xor((int)hb, 1)) << 16);
    unsigned v1 = (unsigned)__shfl_xor((int)v0, 2);
    unsigned v2 = (unsigned)__shfl_xor((int)v0, 4);
    unsigned v3 = (unsigned)__shfl_xor((int)v1, 4);
    if ((tid & 7) == 0) {
        u32x4 pk = { v0, v1, v2, v3 };
        st16_llc((void*)dst16, pk);
    }
}

__global__ void init_ws(unsigned* w) {
    // zero flags (4096 u32), poison both rings (2 * 131072 u32)
    const int total = 4096 + 2 * (RBYTES / 4);
    for (int i = blockIdx.x * 256 + threadIdx.x; i < total; i += gridDim.x * 256)
        w[i] = (i < 4096) ? 0u : POIS32;
}

// Barrier-free dataflow LSTM: per-WG 32x32 output tile, K=1024 over 4 waves,
// mfma_f32_32x32x16_bf16, weights resident in VGPRs. h flows through poisoned
// 16-deep LLC rings; consumers poll fragments directly (no flags, no drains
// on the critical path). Only surviving flag: L1 progress (WAR on h1 ring).
__global__ void __launch_bounds__(256, 1)
lstm_persist(const float* __restrict__ x_in,   // [32][1024][512]
             const float* __restrict__ h0,     // [2][32][512]
             const float* __restrict__ c0,     // [2][32][512]
             const float* __restrict__ Wih,    // [2][2048][512]
             const float* __restrict__ Whh,    // [2][2048][512]
             const float* __restrict__ bih,    // [2][2048]
             const float* __restrict__ bhh,    // [2][2048]
             float* __restrict__ out,
             unsigned char* __restrict__ ws,
             int use_xbf)
{
    __shared__ float gatebuf[4][BATCH][36];
    __shared__ float biasbuf[32];

    const int wg    = blockIdx.x;
    const int layer = (wg >= WGL) ? 1 : 0;
    const int wgl   = wg - layer * WGL;
    const int jbase = wgl * JPW;
    const int tid   = threadIdx.x;

    unsigned* flags = (unsigned*)(ws + WS_FLAGS);
    unsigned short* h1ring = (unsigned short*)(ws + WS_H1);
    unsigned short* h2ring = (unsigned short*)(ws + WS_H2);
    unsigned short* xbf    = (unsigned short*)(ws + WS_XBF);

    // ---- one-time: x -> bf16 in ws (plain stores + release fence) ----
    if (use_xbf) {
        const size_t total4 = (size_t)BATCH * T_STEPS * HID / 4;
        unsigned long long* dst = (unsigned long long*)xbf;
        for (size_t idx = (size_t)wg * 256 + tid; idx < total4; idx += (size_t)NWG * 256) {
            float4 v = *(const float4*)(x_in + idx * 4);
            unsigned long long pk = (unsigned long long)f2bf(v.x)
                                  | ((unsigned long long)f2bf(v.y) << 16)
                                  | ((unsigned long long)f2bf(v.z) << 32)
                                  | ((unsigned long long)f2bf(v.w) << 48);
            dst[idx] = pk;
        }
        __builtin_amdgcn_fence(__ATOMIC_RELEASE, "agent");   // writeback L2 -> LLC
    }

    if (tid < 32) {
        const int g = tid >> 3, jloc = tid & 7;
        const int r = g * HID + jbase + jloc;
        biasbuf[tid] = bih[(size_t)layer * G4 + r] + bhh[(size_t)layer * G4 + r];
    }

    const int lane = tid & 63;
    const int wv   = tid >> 6;          // wave 0..3 = K quarter
    const int hi   = lane >> 5;
    const int l31  = lane & 31;
    const int kb   = (wv & 1) * 256;    // k offset within the 512-wide half

    // ---- weights -> VGPRs (loop-invariant B fragments) ----
    short8 bW[16];
    {
        const float* Wsel = ((wv < 2) ? Wih : Whh) + (size_t)layer * G4 * HID;
        const int r = (l31 >> 3) * HID + jbase + (l31 & 7);   // gate row for col l31
        const float* wr = Wsel + (size_t)r * HID + kb + hi * 8;
        #pragma unroll
        for (int j = 0; j < 16; ++j) {
            float4 v0 = *(const float4*)(wr + j * 16);
            float4 v1 = *(const float4*)(wr + j * 16 + 4);
            short8 p;
            p[0]=(short)f2bf(v0.x); p[1]=(short)f2bf(v0.y); p[2]=(short)f2bf(v0.z); p[3]=(short)f2bf(v0.w);
            p[4]=(short)f2bf(v1.x); p[5]=(short)f2bf(v1.y); p[6]=(short)f2bf(v1.z); p[7]=(short)f2bf(v1.w);
            bW[j] = p;
        }
    }

    const int m  = tid >> 3;
    const int jl = tid & 7;
    const int jg = jbase + jl;

    float creg = c0[((size_t)layer * BATCH + m) * HID + jg];

    // ---- seed: h(-1) = h0 into slot 15 of own ring (fragment stores) ----
    {
        float h0v = h0[((size_t)layer * BATCH + m) * HID + jg];
        unsigned short* ringw = (layer == 0) ? h1ring : h2ring;
        unsigned short* dst = ringw + (((size_t)15 * WGL + wgl) * BATCH + m) * 8;
        publish_row(dst, h0v, tid);
    }

    // ---- one-time global barrier (xbf conversion + seed visibility) ----
    asm volatile("s_waitcnt vmcnt(0)" ::: "memory");
    __syncthreads();
    if (tid == 0)
        __hip_atomic_store(&flags[wg * FPAD], 1u, __ATOMIC_RELAXED, __HIP_MEMORY_SCOPE_AGENT);
    if (tid < NWG) poll_ge(flags + tid * FPAD, 1u);
    __syncthreads();
    __builtin_amdgcn_fence(__ATOMIC_ACQUIRE, "agent");   // one-time inv for xbf plain loads

    short8 afr[16];

#define PREFX(tt)                                                             \
    do {                                                                      \
        if (use_xbf) {                                                        \
            const short* bx = (const short*)xbf +                             \
                ((size_t)l31 * T_STEPS + (tt)) * HID + kb + hi * 8;           \
            _Pragma("unroll")                                                 \
            for (int j = 0; j < 16; ++j)                                      \
                afr[j] = *(const short8*)(bx + j * 16);                       \
        } else {                                                              \
            const float* fx = x_in +                                          \
                ((size_t)l31 * T_STEPS + (tt)) * HID + kb + hi * 8;           \
            _Pragma("unroll")                                                 \
            for (int j = 0; j < 16; ++j) {                                    \
                float4 v0 = *(const float4*)(fx + j * 16);                    \
                float4 v1 = *(const float4*)(fx + j * 16 + 4);                \
                short8 p;                                                     \
                p[0]=(short)f2bf(v0.x); p[1]=(short)f2bf(v0.y);               \
                p[2]=(short)f2bf(v0.z); p[3]=(short)f2bf(v0.w);               \
                p[4]=(short)f2bf(v1.x); p[5]=(short)f2bf(v1.y);               \
                p[6]=(short)f2bf(v1.z); p[7]=(short)f2bf(v1.w);               \
                afr[j] = p;                                                   \
            }                                                                 \
        }                                                                     \
    } while (0)

// Poison-poll 16 fragments into afr from ring `rbase` (shorts; frag stride 512).
#define POLL_FRAGS(rbase)                                                     \
    do {                                                                      \
        for (;;) {                                                            \
            _Pragma("unroll")                                                 \
            for (int j = 0; j < 16; ++j)                                      \
                afr[j] = ld_llc((rbase) + j * 512);                           \
            asm volatile("s_waitcnt vmcnt(0)" ::: "memory");                  \
            int stale = 0;                                                    \
            _Pragma("unroll")                                                 \
            for (int j = 0; j < 16; ++j) {                                    \
                stale |= ((unsigned short)afr[j][0] == (unsigned short)POIS16); \
                stale |= ((unsigned short)afr[j][2] == (unsigned short)POIS16); \
                stale |= ((unsigned short)afr[j][4] == (unsigned short)POIS16); \
                stale |= ((unsigned short)afr[j][6] == (unsigned short)POIS16); \
            }                                                                 \
            if (!__any(stale)) break;                                         \
        }                                                                     \
        __builtin_amdgcn_sched_barrier(0);                                    \
    } while (0)

    if (layer == 0 && wv < 2) PREFX(0);

    // L0: t = s (active 0..1023); L1: t = s-2 (active s = 2..1025)
    const int SE = T_STEPS + 1;                                   // 1025
    for (int s = 0; s <= SE; ++s) {
        const int t = (layer == 0) ? s : s - 2;
        const bool active = (t >= 0) && (t < T_STEPS);
        float hv = 0.0f;

        if (active) {
            if (wv >= 2) {   // h-half: own-layer recurrence, epoch t-1, slot (t-1)&15
                const unsigned short* ring = (layer == 0) ? h1ring : h2ring;
                const int slot = (t + 15) & 15;
                const short* base = (const short*)ring +
                    (((size_t)slot * WGL + (kb >> 3) + hi) * BATCH + l31) * 8;
                POLL_FRAGS(base);
            } else {
                // x-half fragments prefetched (xbf / h1 poll) in prior window
                asm volatile("s_waitcnt vmcnt(0)" ::: "memory");
                __builtin_amdgcn_sched_barrier(0);
            }

            f32x16 acc0, acc1;
            #pragma unroll
            for (int r = 0; r < 16; ++r) { acc0[r] = 0.f; acc1[r] = 0.f; }
            #pragma unroll
            for (int j = 0; j < 16; j += 2) {
                acc0 = __builtin_amdgcn_mfma_f32_32x32x16_bf16(afr[j],     bW[j],     acc0, 0, 0, 0);
                acc1 = __builtin_amdgcn_mfma_f32_32x32x16_bf16(afr[j + 1], bW[j + 1], acc1, 0, 0, 0);
            }
            // C/D layout: col=lane&31, row=(r&3)+8*(r>>2)+4*hi  [verified m74/m101]
            #pragma unroll
            for (int r = 0; r < 16; ++r)
                gatebuf[wv][(r & 3) + 8 * (r >> 2) + 4 * hi][l31] = acc0[r] + acc1[r];
            __syncthreads();

            float gi = gatebuf[0][m][jl]      + gatebuf[1][m][jl]
                     + gatebuf[2][m][jl]      + gatebuf[3][m][jl]      + biasbuf[jl];
            float gf = gatebuf[0][m][8  + jl] + gatebuf[1][m][8  + jl]
                     + gatebuf[2][m][8  + jl] + gatebuf[3][m][8  + jl] + biasbuf[8  + jl];
            float gg = gatebuf[0][m][16 + jl] + gatebuf[1][m][16 + jl]
                     + gatebuf[2][m][16 + jl] + gatebuf[3][m][16 + jl] + biasbuf[16 + jl];
            float go = gatebuf[0][m][24 + jl] + gatebuf[1][m][24 + jl]
                     + gatebuf[2][m][24 + jl] + gatebuf[3][m][24 + jl] + biasbuf[24 + jl];
            float iv = sigm(gi), fv = sigm(gf), gv = ftanh(gg), ov = sigm(go);
            creg = fv * creg + iv * gv;
            hv = ov * ftanh(creg);

            // publish h(t): single 16B fragment stores (the store IS the signal)
            {
                unsigned short* ringw = (layer == 0) ? h1ring : h2ring;
                unsigned short* dst = ringw +
                    (((size_t)(t & 15) * WGL + wgl) * BATCH + m) * 8;
                publish_row(dst, hv, tid);
            }
            if (t == T_STEPS - 1)
                out[H_OFF + ((size_t)layer * BATCH + m) * HID + jg] = hv;
        }

        // ---- window (off the dataflow critical path) ----
        asm volatile("s_waitcnt vmcnt(0)" ::: "memory");   // bound in-flight stores
        __syncthreads();
        if (layer == 1 && tid == 0)   // progress flag (WAR throttle for h1 ring)
            __hip_atomic_store(&flags[wg * FPAD], (unsigned)(s + 2),
                               __ATOMIC_RELAXED, __HIP_MEMORY_SCOPE_AGENT);

        // repoison own slice of slot (t+8)&15 (kills epoch t-8; skew <= ~2)
        {
            unsigned short* ringw = (layer == 0) ? h1ring : h2ring;
            unsigned short* dst = ringw +
                (((size_t)((t + 8) & 15) * WGL + wgl) * BATCH + m) * 8;
            if ((tid & 7) == 0) {
                u32x4 pz = { POIS32, POIS32, POIS32, POIS32 };
                st16_llc((void*)dst, pz);
            }
        }

        if (layer == 1) {
            if (active)
                out[((size_t)m * T_STEPS + t) * HID + jg] = hv;   // [B,T,H]
            if (wv < 2 && t + 1 >= 0 && t + 1 < T_STEPS) {
                // prefetch x-part h1(t+1) = h1(s-1), slot (s-1)&15 (~1 step slack)
                const int slot = (s + 15) & 15;
                const short* base = (const short*)h1ring +
                    (((size_t)slot * WGL + (kb >> 3) + hi) * BATCH + l31) * 8;
                POLL_FRAGS(base);
            }
        } else {
            if (wv < 2 && active && t + 1 < T_STEPS) PREFX(t + 1);
            if (wv == 2 && s >= 3 && lane < WGL)   // WAR: L1 must lag <= ~4 steps
                poll_ge(flags + (WGL + lane) * FPAD, (unsigned)(s - 2));
        }
        __syncthreads();
    }

    out[C_OFF + ((size_t)layer * BATCH + m) * HID + jg] = creg;
#undef PREFX
#undef POLL_FRAGS
}

extern "C" void kernel_launch(void* const* d_in, const int* in_sizes, int n_in,
                              void* d_out, int out_size, void* d_ws, size_t ws_size,
                              hipStream_t stream) {
    const float* x   = (const float*)d_in[0];
    const float* h0  = (const float*)d_in[1];
    const float* c0  = (const float*)d_in[2];
    const float* Wih = (const float*)d_in[3];
    const float* Whh = (const float*)d_in[4];
    const float* bih = (const float*)d_in[5];
    const float* bhh = (const float*)d_in[6];
    float* out = (float*)d_out;
    unsigned char* ws = (unsigned char*)d_ws;

    const size_t xbf_need = (size_t)WS_XBF + (size_t)BATCH * T_STEPS * HID * 2;
    int use_xbf = (ws_size >= xbf_need) ? 1 : 0;

    hipLaunchKernelGGL(init_ws, dim3(64), dim3(256), 0, stream, (unsigned*)ws);

    void* args[] = { (void*)&x, (void*)&h0, (void*)&c0, (void*)&Wih, (void*)&Whh,
                     (void*)&bih, (void*)&bhh, (void*)&out, (void*)&ws, (void*)&use_xbf };
    hipError_t e = hipLaunchCooperativeKernel((void*)lstm_persist, dim3(NWG), dim3(256),
                                              args, 0, stream);
    if (e != hipSuccess) {
        hipLaunchKernelGGL(lstm_persist, dim3(NWG), dim3(256), 0, stream,
                           x, h0, c0, Wih, Whh, bih, bhh, out, ws, use_xbf);
    }
}